// Round 4
// baseline (266.330 us; speedup 1.0000x reference)
//
#include <hip/hip_runtime.h>

#define IN_DIM 8192
#define OUT_DIM 8192
#define NROWS 4096
#define THREADS 512
#define GRID 512
#define RPB (NROWS / GRID)            // 8 rows per persistent block
#define NP (RPB / 2)                  // 4 row-pairs per block
#define JG (OUT_DIM / (THREADS * 4))  // 4 j-groups of 4 consecutive j per thread
#define SV (IN_DIM / (THREADS * 4))   // 4 v4f staging regs per thread per row

static_assert(GRID * RPB == NROWS, "row partition");
static_assert(JG * THREADS * 4 == OUT_DIM, "col partition");
static_assert(SV * THREADS * 4 == IN_DIM, "stage partition");

typedef float v4f __attribute__((ext_vector_type(4)));

// LDS-only block sync: drain this wave's DS ops, barrier. Global loads/stores
// stay in flight (no vmcnt(0) mid-loop).
#define BLOCK_SYNC_LDS()                                   \
  do {                                                     \
    asm volatile("s_waitcnt lgkmcnt(0)" ::: "memory");     \
    __builtin_amdgcn_s_barrier();                          \
    asm volatile("" ::: "memory");                         \
  } while (0)

__device__ __constant__ float GATE_COEF[16][4] = {
    {0.f, 0.f, 0.f, 0.f}, {0.f, 0.f, 0.f, 1.f}, {0.f, 1.f, 0.f, -1.f}, {0.f, 1.f, 0.f, 0.f},
    {0.f, 0.f, 1.f, -1.f}, {0.f, 0.f, 1.f, 0.f}, {0.f, 1.f, 1.f, -2.f}, {0.f, 1.f, 1.f, -1.f},
    {1.f, -1.f, -1.f, 1.f}, {1.f, -1.f, -1.f, 2.f}, {1.f, 0.f, -1.f, 0.f}, {1.f, 0.f, -1.f, 1.f},
    {1.f, -1.f, 0.f, 0.f}, {1.f, -1.f, 0.f, 1.f}, {1.f, 0.f, 0.f, -1.f}, {1.f, 0.f, 0.f, 0.f}};

// Kernel A: c[j] = softmax(weights[j,:]) @ GATE_COEF, SoA planes (coalesced reloads).
__global__ __launch_bounds__(256) void compute_c_kernel(const float* __restrict__ w,
                                                        float* __restrict__ cp) {
  int j = blockIdx.x * blockDim.x + threadIdx.x;
  if (j >= OUT_DIM) return;
  const float4* wv = (const float4*)(w + (size_t)j * 16);
  float4 w0 = wv[0], w1 = wv[1], w2 = wv[2], w3 = wv[3];
  float wa[16] = {w0.x, w0.y, w0.z, w0.w, w1.x, w1.y, w1.z, w1.w,
                  w2.x, w2.y, w2.z, w2.w, w3.x, w3.y, w3.z, w3.w};
  float m = wa[0];
#pragma unroll
  for (int k = 1; k < 16; ++k) m = fmaxf(m, wa[k]);
  float p[16];
  float s = 0.f;
#pragma unroll
  for (int k = 0; k < 16; ++k) {
    p[k] = __expf(wa[k] - m);
    s += p[k];
  }
  float inv = 1.f / s;
  float c0 = 0.f, c1 = 0.f, c2 = 0.f, c3 = 0.f;
#pragma unroll
  for (int k = 0; k < 16; ++k) {
    c0 = fmaf(p[k], GATE_COEF[k][0], c0);
    c1 = fmaf(p[k], GATE_COEF[k][1], c1);
    c2 = fmaf(p[k], GATE_COEF[k][2], c2);
    c3 = fmaf(p[k], GATE_COEF[k][3], c3);
  }
  cp[j] = c0 * inv;
  cp[j + OUT_DIM] = c1 * inv;
  cp[j + 2 * OUT_DIM] = c2 * inv;
  cp[j + 3 * OUT_DIM] = c3 * inv;
}

// Kernel B: paired persistent pipeline. 512 blocks x 512 thr (2 blocks/CU, all
// resident). 4 row-pairs per block; ONE 64 KB LDS pair-buffer; incoming pair
// reg-staged with issue-early/write-late split so the HBM read stream never
// drains. Pairing amortizes idx/c/address work across 2 rows (row-1 gather
// folds to ds_read offset:32768). idx hoisted to regs (row-invariant).
__global__ __launch_bounds__(THREADS, 4) void gate_pairs(
    const float* __restrict__ x, const float* __restrict__ cp,
    const int* __restrict__ idx0, const int* __restrict__ idx1,
    float* __restrict__ out) {
  __shared__ __align__(16) float buf[2 * IN_DIM];  // one row pair, 64 KB
  const int tid = threadIdx.x;
  const int r0 = blockIdx.x * RPB;

  // ---- hoist idx into registers (row-invariant per thread): 32 VGPR ----
  int4 i0[JG], i1[JG];
#pragma unroll
  for (int g = 0; g < JG; ++g) {
    const int j = tid * 4 + g * (THREADS * 4);
    i0[g] = *(const int4*)(idx0 + j);
    i1[g] = *(const int4*)(idx1 + j);
  }

  const float* c0p = cp;
  const float* c1p = cp + OUT_DIM;
  const float* c2p = cp + 2 * OUT_DIM;
  const float* c3p = cp + 3 * OUT_DIM;

  // ---- prologue: pair0 -> LDS via regs; pair1 loads left in flight ----
  v4f ra[2 * SV];  // 32 VGPR: one staged pair
  {
    const float* xr = x + (size_t)r0 * IN_DIM;
#pragma unroll
    for (int row = 0; row < 2; ++row)
#pragma unroll
      for (int t = 0; t < SV; ++t)
        ra[row * SV + t] =
            __builtin_nontemporal_load((const v4f*)(xr + row * IN_DIM) + tid + t * THREADS);
#pragma unroll
    for (int row = 0; row < 2; ++row)
#pragma unroll
      for (int t = 0; t < SV; ++t)
        ((v4f*)(buf + row * IN_DIM))[tid + t * THREADS] = ra[row * SV + t];
    const float* xn = x + (size_t)(r0 + 2) * IN_DIM;
#pragma unroll
    for (int row = 0; row < 2; ++row)
#pragma unroll
      for (int t = 0; t < SV; ++t)
        ra[row * SV + t] =
            __builtin_nontemporal_load((const v4f*)(xn + row * IN_DIM) + tid + t * THREADS);
  }
  BLOCK_SYNC_LDS();

#pragma unroll 1
  for (int p = 0; p < NP; ++p) {
    // (1) compute pair p from LDS (pair p+1 loads in flight since last iter)
    float* o0 = out + (size_t)(r0 + 2 * p) * OUT_DIM;
#pragma unroll
    for (int g = 0; g < JG; ++g) {
      const int j = tid * 4 + g * (THREADS * 4);
      const v4f c0v = *(const v4f*)(c0p + j);
      const v4f c1v = *(const v4f*)(c1p + j);
      const v4f c2v = *(const v4f*)(c2p + j);
      const v4f c3v = *(const v4f*)(c3p + j);
      const int4 ia = i0[g], ib = i1[g];
      v4f a0, b0, a1, b1;  // row-1 gathers fold to ds_read offset:32768
      a0.x = buf[ia.x]; a0.y = buf[ia.y]; a0.z = buf[ia.z]; a0.w = buf[ia.w];
      b0.x = buf[ib.x]; b0.y = buf[ib.y]; b0.z = buf[ib.z]; b0.w = buf[ib.w];
      a1.x = buf[IN_DIM + ia.x]; a1.y = buf[IN_DIM + ia.y];
      a1.z = buf[IN_DIM + ia.z]; a1.w = buf[IN_DIM + ia.w];
      b1.x = buf[IN_DIM + ib.x]; b1.y = buf[IN_DIM + ib.y];
      b1.z = buf[IN_DIM + ib.z]; b1.w = buf[IN_DIM + ib.w];
      const v4f r0v = c0v + c1v * a0 + c2v * b0 + c3v * (a0 * b0);
      const v4f r1v = c0v + c1v * a1 + c2v * b1 + c3v * (a1 * b1);
      __builtin_nontemporal_store(r0v, (v4f*)(o0 + j));
      __builtin_nontemporal_store(r1v, (v4f*)(o0 + OUT_DIM + j));
    }
    // (2) everyone done reading pair p (gather results already consumed)
    BLOCK_SYNC_LDS();
    // (3) publish pair p+1 (its loads had the whole compute phase to land)
    if (p + 1 < NP) {
#pragma unroll
      for (int row = 0; row < 2; ++row)
#pragma unroll
        for (int t = 0; t < SV; ++t)
          ((v4f*)(buf + row * IN_DIM))[tid + t * THREADS] = ra[row * SV + t];
    }
    // (4) issue pair p+2 loads; a full compute phase of latency slack
    if (p + 2 < NP) {
      const float* xn = x + (size_t)(r0 + 2 * (p + 2)) * IN_DIM;
#pragma unroll
      for (int row = 0; row < 2; ++row)
#pragma unroll
        for (int t = 0; t < SV; ++t)
          ra[row * SV + t] =
              __builtin_nontemporal_load((const v4f*)(xn + row * IN_DIM) + tid + t * THREADS);
    }
    // (5) pair p+1 visible to all waves; global traffic stays in flight
    BLOCK_SYNC_LDS();
  }
}

extern "C" void kernel_launch(void* const* d_in, const int* in_sizes, int n_in,
                              void* d_out, int out_size, void* d_ws, size_t ws_size,
                              hipStream_t stream) {
  const float* x = (const float*)d_in[0];
  const float* weights = (const float*)d_in[1];
  const int* idx0 = (const int*)d_in[2];
  const int* idx1 = (const int*)d_in[3];
  float* out = (float*)d_out;
  float* cp = (float*)d_ws;  // 4 planes x OUT_DIM floats = 128 KB scratch

  compute_c_kernel<<<OUT_DIM / 256, 256, 0, stream>>>(weights, cp);
  gate_pairs<<<GRID, THREADS, 0, stream>>>(x, cp, idx0, idx1, out);
}

// Round 5
// 234.461 us; speedup vs baseline: 1.1359x; 1.1359x over previous
//
#include <hip/hip_runtime.h>

#define IN_DIM 8192
#define OUT_DIM 8192
#define NROWS 4096
#define THREADS 512
#define RPB 2                                    // rows per block
#define JITERS (OUT_DIM / (THREADS * 4))         // 4

typedef float v4f __attribute__((ext_vector_type(4)));

// GATE_COEF[16][4] from the reference.
__device__ __constant__ float GATE_COEF[16][4] = {
    {0.f, 0.f, 0.f, 0.f}, {0.f, 0.f, 0.f, 1.f}, {0.f, 1.f, 0.f, -1.f}, {0.f, 1.f, 0.f, 0.f},
    {0.f, 0.f, 1.f, -1.f}, {0.f, 0.f, 1.f, 0.f}, {0.f, 1.f, 1.f, -2.f}, {0.f, 1.f, 1.f, -1.f},
    {1.f, -1.f, -1.f, 1.f}, {1.f, -1.f, -1.f, 2.f}, {1.f, 0.f, -1.f, 0.f}, {1.f, 0.f, -1.f, 1.f},
    {1.f, -1.f, 0.f, 0.f}, {1.f, -1.f, 0.f, 1.f}, {1.f, 0.f, 0.f, -1.f}, {1.f, 0.f, 0.f, 0.f}};

// Kernel A: c[j] = softmax(weights[j,:]) @ GATE_COEF, stored SoA:
// plane p holds cp[j] (OUT_DIM floats each) so gate_kernel's loads coalesce.
__global__ __launch_bounds__(256) void compute_c_kernel(const float* __restrict__ w,
                                                        float* __restrict__ cp) {
    int j = blockIdx.x * blockDim.x + threadIdx.x;
    if (j >= OUT_DIM) return;
    const float4* wv = (const float4*)(w + (size_t)j * 16);
    float4 w0 = wv[0], w1 = wv[1], w2 = wv[2], w3 = wv[3];
    float wa[16] = {w0.x, w0.y, w0.z, w0.w, w1.x, w1.y, w1.z, w1.w,
                    w2.x, w2.y, w2.z, w2.w, w3.x, w3.y, w3.z, w3.w};
    float m = wa[0];
#pragma unroll
    for (int k = 1; k < 16; ++k) m = fmaxf(m, wa[k]);
    float p[16];
    float s = 0.f;
#pragma unroll
    for (int k = 0; k < 16; ++k) {
        p[k] = __expf(wa[k] - m);
        s += p[k];
    }
    float inv = 1.f / s;
    float c0 = 0.f, c1 = 0.f, c2 = 0.f, c3 = 0.f;
#pragma unroll
    for (int k = 0; k < 16; ++k) {
        c0 = fmaf(p[k], GATE_COEF[k][0], c0);
        c1 = fmaf(p[k], GATE_COEF[k][1], c1);
        c2 = fmaf(p[k], GATE_COEF[k][2], c2);
        c3 = fmaf(p[k], GATE_COEF[k][3], c3);
    }
    cp[j] = c0 * inv;
    cp[j + OUT_DIM] = c1 * inv;
    cp[j + 2 * OUT_DIM] = c2 * inv;
    cp[j + 3 * OUT_DIM] = c3 * inv;
}

// Kernel B: measured-best structure (R0: 2 rows/block, 2048 blocks, 8
// generations/CU for cross-block overlap). ONE change vs R0: plain stores
// instead of __builtin_nontemporal_store. R4 counters showed nt stores cause
// 1.6x HBM write amplification (WRITE_SIZE 214 MB for a 134 MB output) via
// partial-line streaming writes; plain stores write back full 64 B lines at
// fill-kernel efficiency (~6.5 TB/s).
__global__ __launch_bounds__(THREADS, 4) void gate_kernel(const float* __restrict__ x,
                                                          const float* __restrict__ cp,
                                                          const int* __restrict__ idx0,
                                                          const int* __restrict__ idx1,
                                                          float* __restrict__ out) {
    __shared__ float rows[RPB * IN_DIM];  // 64 KB
    const int r0 = blockIdx.x * RPB;
    const int tid = threadIdx.x;

    // Stage both rows, coalesced, nontemporal loads (x rows are single-use).
    const v4f* xr0 = (const v4f*)(x + (size_t)r0 * IN_DIM);
    const v4f* xr1 = (const v4f*)(x + (size_t)(r0 + 1) * IN_DIM);
    v4f* rv0 = (v4f*)rows;
    v4f* rv1 = (v4f*)(rows + IN_DIM);
    v4f st[8];
#pragma unroll
    for (int t = 0; t < 4; ++t) st[t] = __builtin_nontemporal_load(xr0 + tid + t * THREADS);
#pragma unroll
    for (int t = 0; t < 4; ++t) st[4 + t] = __builtin_nontemporal_load(xr1 + tid + t * THREADS);

    // Prefetch iteration-0 idx under the staging latency.
    const int j0 = tid * 4;
    int4 pi0 = *(const int4*)(idx0 + j0);
    int4 pi1 = *(const int4*)(idx1 + j0);

#pragma unroll
    for (int t = 0; t < 4; ++t) rv0[tid + t * THREADS] = st[t];
#pragma unroll
    for (int t = 0; t < 4; ++t) rv1[tid + t * THREADS] = st[4 + t];
    __syncthreads();

    const float* __restrict__ c0p = cp;
    const float* __restrict__ c1p = cp + OUT_DIM;
    const float* __restrict__ c2p = cp + 2 * OUT_DIM;
    const float* __restrict__ c3p = cp + 3 * OUT_DIM;
    float* o0 = out + (size_t)r0 * OUT_DIM;
    float* o1 = out + (size_t)(r0 + 1) * OUT_DIM;

#pragma unroll
    for (int k = 0; k < JITERS; ++k) {
        const int j = k * (THREADS * 4) + tid * 4;
        const int4 i0 = pi0;
        const int4 i1 = pi1;
        if (k < JITERS - 1) {
            const int jn = j + THREADS * 4;
            pi0 = *(const int4*)(idx0 + jn);
            pi1 = *(const int4*)(idx1 + jn);
        }
        // Coalesced SoA c loads: each wave instr reads 1 KB contiguous.
        const v4f c0v = *(const v4f*)(c0p + j);
        const v4f c1v = *(const v4f*)(c1p + j);
        const v4f c2v = *(const v4f*)(c2p + j);
        const v4f c3v = *(const v4f*)(c3p + j);
        // Gathers for both rows issued together (16 independent ds_reads).
        v4f a0, b0, a1, b1;
        a0.x = rows[i0.x]; a0.y = rows[i0.y]; a0.z = rows[i0.z]; a0.w = rows[i0.w];
        b0.x = rows[i1.x]; b0.y = rows[i1.y]; b0.z = rows[i1.z]; b0.w = rows[i1.w];
        a1.x = rows[IN_DIM + i0.x]; a1.y = rows[IN_DIM + i0.y];
        a1.z = rows[IN_DIM + i0.z]; a1.w = rows[IN_DIM + i0.w];
        b1.x = rows[IN_DIM + i1.x]; b1.y = rows[IN_DIM + i1.y];
        b1.z = rows[IN_DIM + i1.z]; b1.w = rows[IN_DIM + i1.w];

        const v4f r0v = c0v + c1v * a0 + c2v * b0 + c3v * (a0 * b0);
        const v4f r1v = c0v + c1v * a1 + c2v * b1 + c3v * (a1 * b1);
        // Plain stores: full-line L2 write-back, no nt partial-line amplification.
        *(v4f*)(o0 + j) = r0v;
        *(v4f*)(o1 + j) = r1v;
    }
}

extern "C" void kernel_launch(void* const* d_in, const int* in_sizes, int n_in,
                              void* d_out, int out_size, void* d_ws, size_t ws_size,
                              hipStream_t stream) {
    const float* x = (const float*)d_in[0];
    const float* weights = (const float*)d_in[1];
    const int* idx0 = (const int*)d_in[2];
    const int* idx1 = (const int*)d_in[3];
    float* out = (float*)d_out;
    float* cp = (float*)d_ws;  // 4 planes x OUT_DIM floats = 128 KB scratch

    compute_c_kernel<<<OUT_DIM / 256, 256, 0, stream>>>(weights, cp);
    gate_kernel<<<NROWS / RPB, THREADS, 0, stream>>>(x, cp, idx0, idx1, out);
}